// Round 1
// baseline (63.998 us; speedup 1.0000x reference)
//
#include <hip/hip_runtime.h>
#include <math.h>

// Sizes are fixed by the reference.
#define SEQ   1024
#define BSZ   16
#define DIM   1024
#define SIDE  32
#define DPB   16        // d-channels per block (one b, 16 consecutive d)
#define THREADS 512     // 8 waves; each half-wave (32 lanes) owns one (b,d) image

__device__ __forceinline__ float sigmoidf_(float v) {
    return 1.0f / (1.0f + __expf(-v));
}

// 2D SSM, run as the recurrence directly on x (== causal conv with impulse
// response == reference FFT path, by linearity/shift-invariance/causality):
//   v[i,j] = a2*h[i-1,j] + a1*v[i-1,j] + b2*x[i,j]
//   h[i,j] = a1*h[i,j-1] + a2*v[i,j-1] + b1*x[i,j]
//   y[i,j] = <h,C1*s> + <v,C2*s>;  out = silu(y + x*omega)
// h-recurrence along j solved with a 5-step Kogge-Stone scan (a1 is constant
// along the row, so the scan only needs precomputed a1^{1,2,4,8,16}).
__global__ __launch_bounds__(THREADS) void ssm2d_kernel(
    const float* __restrict__ x,
    const float* __restrict__ A1, const float* __restrict__ A2,
    const float* __restrict__ B1, const float* __restrict__ B2,
    const float* __restrict__ C1, const float* __restrict__ C2,
    const float* __restrict__ omega,
    float* __restrict__ out)
{
    // [dd][s ^ (2*dd)] swizzled layout: staging writes and row-reads are
    // both <=2-way bank conflicts (free).
    __shared__ float xs[DPB * 1024];   // 64 KB

    const int bx   = blockIdx.x;       // 0..1023
    const int b    = bx >> 6;          // 0..15
    const int dblk = bx & 63;          // 0..63
    const int d0   = dblk * DPB;
    const int t    = threadIdx.x;

    // ---- stage x (s in [0,1024), dd in [0,16)) into LDS, coalesced float4 ----
    const float* xb = x + (size_t)b * DIM + d0;
    #pragma unroll
    for (int k = 0; k < 8; ++k) {
        int g = t + k * THREADS;       // 0..4095 float4-groups
        int s = g >> 2;
        int q = g & 3;                 // which float4 of the 16 dds
        const float4 v = *reinterpret_cast<const float4*>(
            xb + (size_t)s * (BSZ * DIM) + 4 * q);
        int dd0 = 4 * q;
        xs[(dd0 + 0) * 1024 + (s ^ (2 * (dd0 + 0)))] = v.x;
        xs[(dd0 + 1) * 1024 + (s ^ (2 * (dd0 + 1)))] = v.y;
        xs[(dd0 + 2) * 1024 + (s ^ (2 * (dd0 + 2)))] = v.z;
        xs[(dd0 + 3) * 1024 + (s ^ (2 * (dd0 + 3)))] = v.w;
    }

    // ---- per-lane setup: coefficients for this lane's channel d ----
    const int lane = t & 63;
    const int w    = t >> 6;               // wave id 0..7
    const int dd   = 2 * w + (lane >> 5);  // image within block, 0..15
    const int j    = lane & 31;            // column
    const int d    = d0 + dd;

    float a1[2], a2[2], b1[2], b2[2], c1s[2], c2s[2];
    float p1[2], p2[2], p4[2], p8[2], p16[2];
    #pragma unroll
    for (int c = 0; c < 2; ++c) {
        a1[c] = sigmoidf_(A1[d * 2 + c]) * 0.5f;
        a2[c] = sigmoidf_(A2[d * 2 + c]) * 0.5f;
        b1[c] = sigmoidf_(B1[d * 2 + c]) * 0.5f;
        b2[c] = sigmoidf_(B2[d * 2 + c]) * 0.5f;
        c1s[c] = C1[d * 2 + c] * 0.70710678118654752f;  // * sqrt(1/NDIM)
        c2s[c] = C2[d * 2 + c] * 0.70710678118654752f;
        p1[c]  = a1[c];
        p2[c]  = p1[c] * p1[c];
        p4[c]  = p2[c] * p2[c];
        p8[c]  = p4[c] * p4[c];
        p16[c] = p8[c] * p8[c];
    }
    const float om = omega[d];

    __syncthreads();

    // ---- recurrence over rows; columns across the 32 lanes ----
    const int ddbase = dd * 1024;
    const int sw     = 2 * dd;
    float hprev0 = 0.f, hprev1 = 0.f, vprev0 = 0.f, vprev1 = 0.f;

    for (int i = 0; i < SIDE; ++i) {
        const int s  = i * SIDE + j;
        const float xv = xs[ddbase + (s ^ sw)];

        // v[i,j] = a2*h[i-1,j] + a1*v[i-1,j] + b2*x
        float v0 = fmaf(a2[0], hprev0, fmaf(a1[0], vprev0, b2[0] * xv));
        float v1 = fmaf(a2[1], hprev1, fmaf(a1[1], vprev1, b2[1] * xv));

        // sv = v[i,j-1]
        float sv0 = __shfl_up(v0, 1, 32); sv0 = (j >= 1) ? sv0 : 0.f;
        float sv1 = __shfl_up(v1, 1, 32); sv1 = (j >= 1) ? sv1 : 0.f;

        // c_j = a2*sv + b1*x ;  h_j = a1*h_{j-1} + c_j  (scan)
        float t0 = fmaf(a2[0], sv0, b1[0] * xv);
        float t1 = fmaf(a2[1], sv1, b1[1] * xv);

        float u;
        u = __shfl_up(t0, 1, 32);  t0 = fmaf(p1[0],  (j >= 1)  ? u : 0.f, t0);
        u = __shfl_up(t1, 1, 32);  t1 = fmaf(p1[1],  (j >= 1)  ? u : 0.f, t1);
        u = __shfl_up(t0, 2, 32);  t0 = fmaf(p2[0],  (j >= 2)  ? u : 0.f, t0);
        u = __shfl_up(t1, 2, 32);  t1 = fmaf(p2[1],  (j >= 2)  ? u : 0.f, t1);
        u = __shfl_up(t0, 4, 32);  t0 = fmaf(p4[0],  (j >= 4)  ? u : 0.f, t0);
        u = __shfl_up(t1, 4, 32);  t1 = fmaf(p4[1],  (j >= 4)  ? u : 0.f, t1);
        u = __shfl_up(t0, 8, 32);  t0 = fmaf(p8[0],  (j >= 8)  ? u : 0.f, t0);
        u = __shfl_up(t1, 8, 32);  t1 = fmaf(p8[1],  (j >= 8)  ? u : 0.f, t1);
        u = __shfl_up(t0, 16, 32); t0 = fmaf(p16[0], (j >= 16) ? u : 0.f, t0);
        u = __shfl_up(t1, 16, 32); t1 = fmaf(p16[1], (j >= 16) ? u : 0.f, t1);
        // t0,t1 = h[i,j]

        float y = t0 * c1s[0] + t1 * c1s[1] + v0 * c2s[0] + v1 * c2s[1];
        float z = fmaf(xv, om, y);            // + residual
        float o = z * sigmoidf_(z);           // silu

        xs[ddbase + (s ^ sw)] = o;            // in-place; only this lane touches it

        hprev0 = t0; hprev1 = t1; vprev0 = v0; vprev1 = v1;
    }

    __syncthreads();

    // ---- coalesced float4 store-out (same pattern as staging) ----
    float* ob = out + (size_t)b * DIM + d0;
    #pragma unroll
    for (int k = 0; k < 8; ++k) {
        int g = t + k * THREADS;
        int s = g >> 2;
        int q = g & 3;
        int dd0 = 4 * q;
        float4 v;
        v.x = xs[(dd0 + 0) * 1024 + (s ^ (2 * (dd0 + 0)))];
        v.y = xs[(dd0 + 1) * 1024 + (s ^ (2 * (dd0 + 1)))];
        v.z = xs[(dd0 + 2) * 1024 + (s ^ (2 * (dd0 + 2)))];
        v.w = xs[(dd0 + 3) * 1024 + (s ^ (2 * (dd0 + 3)))];
        *reinterpret_cast<float4*>(ob + (size_t)s * (BSZ * DIM) + 4 * q) = v;
    }
}

extern "C" void kernel_launch(void* const* d_in, const int* in_sizes, int n_in,
                              void* d_out, int out_size, void* d_ws, size_t ws_size,
                              hipStream_t stream) {
    const float* x     = (const float*)d_in[0];
    const float* A1    = (const float*)d_in[1];
    const float* A2    = (const float*)d_in[2];
    const float* B1    = (const float*)d_in[3];
    const float* B2    = (const float*)d_in[4];
    const float* C1    = (const float*)d_in[5];
    const float* C2    = (const float*)d_in[6];
    const float* omega = (const float*)d_in[7];
    float* out = (float*)d_out;

    dim3 grid(BSZ * (DIM / DPB));   // 16 * 64 = 1024 blocks
    dim3 block(THREADS);
    hipLaunchKernelGGL(ssm2d_kernel, grid, block, 0, stream,
                       x, A1, A2, B1, B2, C1, C2, omega, out);
}